// Round 12
// baseline (1113.033 us; speedup 1.0000x reference)
//
#include <hip/hip_runtime.h>
#include <hip/hip_bf16.h>
#include <stdint.h>

typedef __attribute__((ext_vector_type(8))) short bf16x8;
typedef __attribute__((ext_vector_type(4))) float f32x4;
typedef __attribute__((ext_vector_type(4))) int i32x4;

constexpr int Mdim = 8192;
constexpr int Ndim = 11008;
constexpr int Kdim = 4096;
constexpr int NT = Kdim / 64;                       // 64 K-tiles of BK=64
constexpr int NWG = (Mdim / 256) * (Ndim / 256);    // 1376
constexpr int CPX = NWG / 8;                        // 172
constexpr int NBN = Ndim / 256;                     // 43

__device__ __forceinline__ unsigned short f2bf(float f) {
    __bf16 h = (__bf16)f;
    return __builtin_bit_cast(unsigned short, h);
}

__device__ __forceinline__ void gload16(const unsigned short* g, unsigned short* lds) {
    __builtin_amdgcn_global_load_lds(
        (const __attribute__((address_space(1))) unsigned int*)g,
        (__attribute__((address_space(3))) unsigned int*)lds,
        16, 0, 0);
}

// ---------------- fused prepass: A fp32->bf16  ||  W int4->dequant bf16 [N][K] ----------------
__global__ __launch_bounds__(256) void prep_kernel(const float* __restrict__ A,
                                                   unsigned short* __restrict__ Ab,
                                                   const int* __restrict__ Wq,
                                                   const float* __restrict__ Ws,
                                                   unsigned short* __restrict__ Wt)
{
    __shared__ unsigned short T[64][72];
    const int t = threadIdx.x;
    if (blockIdx.x < 4096) {
        const size_t total8 = (size_t)Mdim * Kdim / 8;
        for (size_t i = (size_t)blockIdx.x * 256 + t; i < total8; i += (size_t)4096 * 256) {
            const float* src = A + i * 8;
            const f32x4 x0 = *(const f32x4*)src;
            const f32x4 x1 = *(const f32x4*)(src + 4);
            union { bf16x8 v; unsigned short u[8]; } h;
            h.u[0] = f2bf(x0[0]); h.u[1] = f2bf(x0[1]);
            h.u[2] = f2bf(x0[2]); h.u[3] = f2bf(x0[3]);
            h.u[4] = f2bf(x1[0]); h.u[5] = f2bf(x1[1]);
            h.u[6] = f2bf(x1[2]); h.u[7] = f2bf(x1[3]);
            *(bf16x8*)(Ab + i * 8) = h.v;
        }
        return;
    }
    const int wb = blockIdx.x - 4096;
    const int kt = wb % (Kdim / 64);
    const int nt = wb / (Kdim / 64);
    const int k0 = kt * 64, n0 = nt * 64;

    const int pr   = t >> 3;
    const int nloc = (t & 7) * 8;
    const int* wp = Wq + (size_t)(k0 / 2 + pr) * Ndim + n0 + nloc;
    const i32x4 ra = *(const i32x4*)wp;
    const i32x4 rb = *(const i32x4*)(wp + 4);
    const int g = (k0 + 2 * pr) >> 5;
    const float* sp = Ws + (size_t)g * Ndim + n0 + nloc;
    const f32x4 s0 = *(const f32x4*)sp;
    const f32x4 s1 = *(const f32x4*)(sp + 4);
#pragma unroll
    for (int i = 0; i < 8; ++i) {
        const int v = (i < 4) ? ra[i] : rb[i - 4];
        const float s = (i < 4) ? s0[i] : s1[i - 4];
        union { unsigned int w; unsigned short u[2]; } o;
        o.u[0] = f2bf((float)((v & 15) - 8) * s);
        o.u[1] = f2bf((float)(((v >> 4) & 15) - 8) * s);
        *(unsigned int*)&T[nloc + i][2 * pr] = o.w;
    }
    __syncthreads();
    const int nl = t >> 2;
    const int ko = (t & 3) * 16;
    bf16x8 o0 = *(const bf16x8*)&T[nl][ko];
    bf16x8 o1 = *(const bf16x8*)&T[nl][ko + 8];
    unsigned short* dst = Wt + (size_t)(n0 + nl) * Kdim + k0 + ko;
    *(bf16x8*)dst = o0;
    *(bf16x8*)(dst + 8) = o1;
}

// ---- main GEMM: 256x256x64, 8 waves; A via LDS (64KB dbuf), B streamed to registers ----
__global__ __launch_bounds__(512, 2) void gemm256_kernel(
    const unsigned short* __restrict__ Ab,
    const unsigned short* __restrict__ Bt,
    const float* __restrict__ Bias,
    float* __restrict__ Out)
{
    // A only: 4 slots (par,half) of 128x64 bf16 = 64 KiB
    __shared__ unsigned short sh[32768];

    const int tid  = threadIdx.x;
    const int lane = tid & 63;
    const int wid  = tid >> 6;
    const int wr   = wid >> 2;               // 0..1 : M 128-row half
    const int wc   = wid & 3;                // 0..3 : N 64-col quarter
    const int l15  = lane & 15;
    const int l4   = lane >> 4;
    const int swz  = (l15 & 7) << 3;
    const int kb0  = l4 * 8;
    const int kb1  = 32 + l4 * 8;

    // XCD-aware bijective swizzle (1376 % 8 == 0), bm-major chunks per XCD
    const int wg  = ((int)blockIdx.x % 8) * CPX + (int)blockIdx.x / 8;
    const int bm = wg / NBN, bn = wg % NBN;
    const int m0 = bm * 256, n0 = bn * 256;

    // A staging (pre-swizzled source, linear LDS dest)
    const int sr  = tid >> 3;
    const int scl = ((tid & 7) * 8) ^ ((sr & 7) << 3);
    const int ldo = sr * 64 + (tid & 7) * 8;
    const unsigned short* aSrc = Ab + (size_t)(m0 + sr) * Kdim + scl;

    auto stageA = [&](int tt, int h, int slot) {
        unsigned short* base = &sh[slot * 8192];
#pragma unroll
        for (int j = 0; j < 2; ++j)
            gload16(aSrc + (size_t)(h * 128 + 64 * j) * Kdim + tt * 64, base + ldo + j * 4096);
    };

    // B register streaming: per-wave quarter, 8 x dwordx4 per tile
    const unsigned short* bBase = Bt + (size_t)(n0 + wc * 64 + l15) * Kdim + l4 * 8;

#define LOADB(TT, DST)                                                        \
    {                                                                         \
        _Pragma("unroll")                                                     \
        for (int fn = 0; fn < 4; ++fn) {                                      \
            _Pragma("unroll")                                                 \
            for (int ks = 0; ks < 2; ++ks)                                    \
                DST[fn][ks] = *(const bf16x8*)(bBase +                        \
                    (size_t)fn * 16 * Kdim + (TT) * 64 + ks * 32);            \
        }                                                                     \
    }

    f32x4 acc[8][4];
#pragma unroll
    for (int i = 0; i < 8; ++i)
#pragma unroll
        for (int j = 0; j < 4; ++j) acc[i][j] = (f32x4){0.f, 0.f, 0.f, 0.f};

    bf16x8 bP[4][2], bQ[4][2];

    // prologue: stage A(0), load B(0) to bP; drain; barrier
    stageA(0, 0, 0); stageA(0, 1, 1);
    LOADB(0, bP);
    asm volatile("s_waitcnt vmcnt(0)" ::: "memory");
    __builtin_amdgcn_s_barrier();

#define TILE(T, BCUR, BNXT, PAR)                                              \
    {                                                                         \
        const unsigned short* aslot = &sh[((PAR) * 2 + wr) * 8192];           \
        if ((T) + 1 < NT) {                                                   \
            LOADB((T) + 1, BNXT);                                             \
            stageA((T) + 1, 0, (1 - (PAR)) * 2 + 0);                          \
            stageA((T) + 1, 1, (1 - (PAR)) * 2 + 1);                          \
        }                                                                     \
        asm volatile("" ::: "memory");                                        \
        bf16x8 aP[2][2], aQ[2][2];                                            \
        _Pragma("unroll")                                                     \
        for (int q = 0; q < 2; ++q) {                                         \
            const int row = q * 16 + l15;                                     \
            aP[q][0] = *(const bf16x8*)&aslot[row * 64 + (kb0 ^ swz)];        \
            aP[q][1] = *(const bf16x8*)&aslot[row * 64 + (kb1 ^ swz)];        \
        }                                                                     \
        _Pragma("unroll")                                                     \
        for (int q = 0; q < 2; ++q) {                                         \
            const int row = (2 + q) * 16 + l15;                               \
            aQ[q][0] = *(const bf16x8*)&aslot[row * 64 + (kb0 ^ swz)];        \
            aQ[q][1] = *(const bf16x8*)&aslot[row * 64 + (kb1 ^ swz)];        \
        }                                                                     \
        __builtin_amdgcn_s_setprio(1);                                        \
        _Pragma("unroll")                                                     \
        for (int ks = 0; ks < 2; ++ks) {                                      \
            _Pragma("unroll")                                                 \
            for (int q = 0; q < 2; ++q) {                                     \
                _Pragma("unroll")                                             \
                for (int fn = 0; fn < 4; ++fn)                                \
                    acc[q][fn] = __builtin_amdgcn_mfma_f32_16x16x32_bf16(     \
                        aP[q][ks], BCUR[fn][ks], acc[q][fn], 0, 0, 0);        \
            }                                                                 \
        }                                                                     \
        __builtin_amdgcn_s_setprio(0);                                        \
        _Pragma("unroll")                                                     \
        for (int q = 0; q < 2; ++q) {                                         \
            const int row = (4 + q) * 16 + l15;                               \
            aP[q][0] = *(const bf16x8*)&aslot[row * 64 + (kb0 ^ swz)];        \
            aP[q][1] = *(const bf16x8*)&aslot[row * 64 + (kb1 ^ swz)];        \
        }                                                                     \
        __builtin_amdgcn_s_setprio(1);                                        \
        _Pragma("unroll")                                                     \
        for (int ks = 0; ks < 2; ++ks) {                                      \
            _Pragma("unroll")                                                 \
            for (int q = 0; q < 2; ++q) {                                     \
                _Pragma("unroll")                                             \
                for (int fn = 0; fn < 4; ++fn)                                \
                    acc[2 + q][fn] = __builtin_amdgcn_mfma_f32_16x16x32_bf16( \
                        aQ[q][ks], BCUR[fn][ks], acc[2 + q][fn], 0, 0, 0);    \
            }                                                                 \
        }                                                                     \
        __builtin_amdgcn_s_setprio(0);                                        \
        _Pragma("unroll")                                                     \
        for (int q = 0; q < 2; ++q) {                                         \
            const int row = (6 + q) * 16 + l15;                               \
            aQ[q][0] = *(const bf16x8*)&aslot[row * 64 + (kb0 ^ swz)];        \
            aQ[q][1] = *(const bf16x8*)&aslot[row * 64 + (kb1 ^ swz)];        \
        }                                                                     \
        __builtin_amdgcn_s_setprio(1);                                        \
        _Pragma("unroll")                                                     \
        for (int ks = 0; ks < 2; ++ks) {                                      \
            _Pragma("unroll")                                                 \
            for (int q = 0; q < 2; ++q) {                                     \
                _Pragma("unroll")                                             \
                for (int fn = 0; fn < 4; ++fn)                                \
                    acc[4 + q][fn] = __builtin_amdgcn_mfma_f32_16x16x32_bf16( \
                        aP[q][ks], BCUR[fn][ks], acc[4 + q][fn], 0, 0, 0);    \
            }                                                                 \
        }                                                                     \
        _Pragma("unroll")                                                     \
        for (int ks = 0; ks < 2; ++ks) {                                      \
            _Pragma("unroll")                                                 \
            for (int q = 0; q < 2; ++q) {                                     \
                _Pragma("unroll")                                             \
                for (int fn = 0; fn < 4; ++fn)                                \
                    acc[6 + q][fn] = __builtin_amdgcn_mfma_f32_16x16x32_bf16( \
                        aQ[q][ks], BCUR[fn][ks], acc[6 + q][fn], 0, 0, 0);    \
            }                                                                 \
        }                                                                     \
        __builtin_amdgcn_s_setprio(0);                                        \
        asm volatile("s_waitcnt vmcnt(0)" ::: "memory");                      \
        __builtin_amdgcn_s_barrier();                                         \
    }

    for (int t2 = 0; t2 < NT; t2 += 2) {
        TILE(t2,     bP, bQ, 0);
        TILE(t2 + 1, bQ, bP, 1);
    }

    // ---- epilogue: C/D col = lane&15, row = (lane>>4)*4 + r ----
    const int rb = l4 * 4;
    float bv[4];
#pragma unroll
    for (int fn = 0; fn < 4; ++fn)
        bv[fn] = Bias[n0 + wc * 64 + fn * 16 + l15];
#pragma unroll
    for (int fm = 0; fm < 8; ++fm) {
        const size_t mg = (size_t)(m0 + wr * 128 + fm * 16 + rb);
#pragma unroll
        for (int fn = 0; fn < 4; ++fn) {
            const int ng = n0 + wc * 64 + fn * 16 + l15;
            const float bb = bv[fn];
#pragma unroll
            for (int r = 0; r < 4; ++r)
                Out[(mg + r) * Ndim + ng] = acc[fm][fn][r] + bb;
        }
    }
}

// ---------------- fallback: fused kernel (if ws too small) ----------------
constexpr int SA = 72;
__global__ __launch_bounds__(256) void w4a32_fused_kernel(
    const float* __restrict__ A,
    const int* __restrict__ Wq,
    const float* __restrict__ Ws,
    const float* __restrict__ Bias,
    float* __restrict__ Out)
{
    __shared__ unsigned short As[128 * SA];
    __shared__ unsigned short Bs[128 * SA];
    const int tid = threadIdx.x;
    const int nbn = Ndim / 128;
    const int bn = blockIdx.x % nbn;
    const int bm = blockIdx.x / nbn;
    const int m0 = bm * 128, n0 = bn * 128;
    const int lane = tid & 63;
    const int wid  = tid >> 6;
    const int wr   = wid >> 1;
    const int wc   = wid & 1;
    const int l15  = lane & 15;
    const int l4   = lane >> 4;
    f32x4 acc[4][4];
#pragma unroll
    for (int i = 0; i < 4; ++i)
#pragma unroll
        for (int j = 0; j < 4; ++j) acc[i][j] = (f32x4){0.f, 0.f, 0.f, 0.f};
    const int a_tr = tid >> 3;
    const int a_tc = (tid & 7) * 8;
    const int kp2  = tid >> 4;
    const int n8   = (tid & 15) * 8;
    for (int kt = 0; kt < Kdim / 64; ++kt) {
        const int k0 = kt * 64;
        __syncthreads();
#pragma unroll
        for (int j = 0; j < 4; ++j) {
            const int ml = a_tr + 32 * j;
            const float* src = A + (size_t)(m0 + ml) * Kdim + (k0 + a_tc);
            const f32x4 x0 = *(const f32x4*)src;
            const f32x4 x1 = *(const f32x4*)(src + 4);
            union { bf16x8 v; unsigned short u[8]; } h;
            h.u[0] = f2bf(x0[0]); h.u[1] = f2bf(x0[1]);
            h.u[2] = f2bf(x0[2]); h.u[3] = f2bf(x0[3]);
            h.u[4] = f2bf(x1[0]); h.u[5] = f2bf(x1[1]);
            h.u[6] = f2bf(x1[2]); h.u[7] = f2bf(x1[3]);
            *(bf16x8*)(&As[ml * SA + (a_tc ^ ((ml & 7) << 3))]) = h.v;
        }
        {
            const int pr = kt * 32 + 2 * kp2;
            const int* wp = Wq + (size_t)pr * Ndim + (n0 + n8);
            const i32x4 r0a = *(const i32x4*)wp;
            const i32x4 r0b = *(const i32x4*)(wp + 4);
            const i32x4 r1a = *(const i32x4*)(wp + Ndim);
            const i32x4 r1b = *(const i32x4*)(wp + Ndim + 4);
            const int g = 2 * kt + (kp2 >> 3);
            const float* sp = Ws + (size_t)g * Ndim + (n0 + n8);
            const f32x4 s0 = *(const f32x4*)sp;
            const f32x4 s1 = *(const f32x4*)(sp + 4);
#pragma unroll
            for (int i = 0; i < 8; ++i) {
                const float s = (i < 4) ? s0[i] : s1[i - 4];
                const int b0 = (i < 4) ? r0a[i] : r0b[i - 4];
                const int b1 = (i < 4) ? r1a[i] : r1b[i - 4];
                union { unsigned long long v; unsigned short u[4]; } o;
                o.u[0] = f2bf((float)((b0 & 15) - 8) * s);
                o.u[1] = f2bf((float)(((b0 >> 4) & 15) - 8) * s);
                o.u[2] = f2bf((float)((b1 & 15) - 8) * s);
                o.u[3] = f2bf((float)(((b1 >> 4) & 15) - 8) * s);
                const int nl = n8 + i;
                const int swzz = ((nl ^ (nl >> 3)) & 7) << 3;
                *(unsigned long long*)(&Bs[nl * SA + ((4 * kp2) ^ swzz)]) = o.v;
            }
        }
        __syncthreads();
#pragma unroll
        for (int ks = 0; ks < 2; ++ks) {
            const int kb  = ks * 32 + l4 * 8;
            const int swa = (l15 & 7) << 3;
            bf16x8 af[4], bfr[4];
#pragma unroll
            for (int fm = 0; fm < 4; ++fm) {
                const int row = wr * 64 + fm * 16 + l15;
                af[fm] = *(const bf16x8*)(&As[row * SA + (kb ^ swa)]);
            }
#pragma unroll
            for (int fn = 0; fn < 4; ++fn) {
                const int nrow = wc * 64 + fn * 16 + l15;
                const int swb = ((nrow ^ (nrow >> 3)) & 7) << 3;
                bfr[fn] = *(const bf16x8*)(&Bs[nrow * SA + (kb ^ swb)]);
            }
#pragma unroll
            for (int fm = 0; fm < 4; ++fm)
#pragma unroll
                for (int fn = 0; fn < 4; ++fn)
                    acc[fm][fn] = __builtin_amdgcn_mfma_f32_16x16x32_bf16(
                        af[fm], bfr[fn], acc[fm][fn], 0, 0, 0);
        }
    }
    const int rb = l4 * 4;
    float bv[4];
#pragma unroll
    for (int fn = 0; fn < 4; ++fn)
        bv[fn] = Bias[n0 + wc * 64 + fn * 16 + l15];
#pragma unroll
    for (int fm = 0; fm < 4; ++fm) {
        const size_t mg = (size_t)(m0 + wr * 64 + fm * 16 + rb);
#pragma unroll
        for (int fn = 0; fn < 4; ++fn) {
            const int ng = n0 + wc * 64 + fn * 16 + l15;
            const float b = bv[fn];
#pragma unroll
            for (int r = 0; r < 4; ++r)
                Out[(mg + r) * Ndim + ng] = acc[fm][fn][r] + b;
        }
    }
}

extern "C" void kernel_launch(void* const* d_in, const int* in_sizes, int n_in,
                              void* d_out, int out_size, void* d_ws, size_t ws_size,
                              hipStream_t stream) {
    const float* A    = (const float*)d_in[0];
    const int* Wq     = (const int*)d_in[1];
    const float* Ws   = (const float*)d_in[2];
    const float* Bias = (const float*)d_in[3];
    float* Out        = (float*)d_out;

    const size_t needA = (size_t)Mdim * Kdim * 2;
    const size_t needW = (size_t)Ndim * Kdim * 2;
    const int prepGrid = 4096 + (Kdim / 64) * (Ndim / 64);

    if (ws_size >= needA + needW) {
        unsigned short* Ab = (unsigned short*)d_ws;
        unsigned short* Wt = (unsigned short*)((char*)d_ws + needA);
        prep_kernel<<<prepGrid, 256, 0, stream>>>(A, Ab, Wq, Ws, Wt);
        gemm256_kernel<<<NWG, 512, 0, stream>>>(Ab, Wt, Bias, Out);
    } else {
        w4a32_fused_kernel<<<(Mdim / 128) * (Ndim / 128), 256, 0, stream>>>(A, Wq, Ws, Bias, Out);
    }
}

// Round 13
// 528.237 us; speedup vs baseline: 2.1071x; 2.1071x over previous
//
#include <hip/hip_runtime.h>
#include <hip/hip_bf16.h>
#include <stdint.h>

typedef __attribute__((ext_vector_type(8))) short bf16x8;
typedef __attribute__((ext_vector_type(4))) float f32x4;
typedef __attribute__((ext_vector_type(4))) int i32x4;

constexpr int Mdim = 8192;
constexpr int Ndim = 11008;
constexpr int Kdim = 4096;
constexpr int NT = Kdim / 64;                       // 64 K-tiles of BK=64
constexpr int NWG = (Mdim / 256) * (Ndim / 256);    // 1376
constexpr int CPX = NWG / 8;                        // 172
constexpr int NBN = Ndim / 256;                     // 43

__device__ __forceinline__ unsigned short f2bf(float f) {
    __bf16 h = (__bf16)f;
    return __builtin_bit_cast(unsigned short, h);
}

__device__ __forceinline__ void gload16(const void* g, void* lds) {
    __builtin_amdgcn_global_load_lds(
        (const __attribute__((address_space(1))) unsigned int*)g,
        (__attribute__((address_space(3))) unsigned int*)lds,
        16, 0, 0);
}

// ---------------- prepass 1: A fp32 -> i8 per-row absmax scale ----------------
__global__ __launch_bounds__(256) void quantA_kernel(const float* __restrict__ A,
                                                     char* __restrict__ Aq,
                                                     float* __restrict__ sA)
{
    __shared__ float red[4];
    const int row = blockIdx.x;
    const int tid = threadIdx.x;
    const float* src = A + (size_t)row * Kdim + tid * 16;
    f32x4 v[4];
    float m = 0.f;
#pragma unroll
    for (int j = 0; j < 4; ++j) {
        v[j] = *(const f32x4*)(src + j * 4);
#pragma unroll
        for (int e = 0; e < 4; ++e) m = fmaxf(m, fabsf(v[j][e]));
    }
#pragma unroll
    for (int o = 32; o > 0; o >>= 1) m = fmaxf(m, __shfl_down(m, o));
    if ((tid & 63) == 0) red[tid >> 6] = m;
    __syncthreads();
    m = fmaxf(fmaxf(red[0], red[1]), fmaxf(red[2], red[3]));
    const float inv = 127.0f / m;
    if (tid == 0) sA[row] = m * (1.0f / 127.0f);
    char out[16];
#pragma unroll
    for (int j = 0; j < 4; ++j)
#pragma unroll
        for (int e = 0; e < 4; ++e)
            out[j * 4 + e] = (char)__float2int_rn(v[j][e] * inv);
    *(i32x4*)(Aq + (size_t)row * Kdim + tid * 16) = *(const i32x4*)out;
}

// ---------------- prepass 2a: per-column fold factor from group scales ----------------
__global__ __launch_bounds__(256) void wscale_kernel(const float* __restrict__ Ws,
                                                     float* __restrict__ Fc,
                                                     float* __restrict__ sCol)
{
    const int n = blockIdx.x * 256 + threadIdx.x;      // 43*256 = 11008 exact
    float mx = 0.f;
    for (int g = 0; g < 128; ++g) mx = fmaxf(mx, Ws[(size_t)g * Ndim + n]);
    Fc[n]   = 15.875f / mx;                            // 127/(8*mx)
    sCol[n] = mx * (8.0f / 127.0f);
}

// ---------------- prepass 2b: W int4 -> i8 (scale-folded), transposed [N][K] ----------------
__global__ __launch_bounds__(256) void wq_kernel(const int* __restrict__ Wq,
                                                 const float* __restrict__ Ws,
                                                 const float* __restrict__ Fc,
                                                 char* __restrict__ Wt)
{
    __shared__ char T[64][80];
    const int kt = blockIdx.x % (Kdim / 64);
    const int nt = blockIdx.x / (Kdim / 64);
    const int k0 = kt * 64, n0 = nt * 64;
    const int t = threadIdx.x;

    const int pr   = t >> 3;                 // 0..31 packed row
    const int nloc = (t & 7) * 8;
    const int* wp = Wq + (size_t)(k0 / 2 + pr) * Ndim + n0 + nloc;
    const i32x4 ra = *(const i32x4*)wp;
    const i32x4 rb = *(const i32x4*)(wp + 4);
    const int g = (k0 + 2 * pr) >> 5;
    const float* sp = Ws + (size_t)g * Ndim + n0 + nloc;
    const f32x4 s0 = *(const f32x4*)sp;
    const f32x4 s1 = *(const f32x4*)(sp + 4);
    const f32x4 f0 = *(const f32x4*)(Fc + n0 + nloc);
    const f32x4 f1 = *(const f32x4*)(Fc + n0 + nloc + 4);
#pragma unroll
    for (int i = 0; i < 8; ++i) {
        const int v = (i < 4) ? ra[i] : rb[i - 4];
        const float sf = ((i < 4) ? s0[i] : s1[i - 4]) * ((i < 4) ? f0[i] : f1[i - 4]);
        T[nloc + i][2 * pr]     = (char)__float2int_rn((float)((v & 15) - 8) * sf);
        T[nloc + i][2 * pr + 1] = (char)__float2int_rn((float)(((v >> 4) & 15) - 8) * sf);
    }
    __syncthreads();
    const int nl = t >> 2;
    const int ko = (t & 3) * 16;
    const i32x4 o = *(const i32x4*)&T[nl][ko];
    *(i32x4*)(Wt + (size_t)(n0 + nl) * Kdim + k0 + ko) = o;
}

// ---- main GEMM: 256x256x64, 8 waves, i8 MFMA K=64, R9 schedule, 2 barriers/K-tile ----
__global__ __launch_bounds__(512, 2) void gemm_i8_kernel(
    const char* __restrict__ Ab,
    const char* __restrict__ Bt,
    const float* __restrict__ sA,
    const float* __restrict__ sCol,
    const float* __restrict__ Bias,
    float* __restrict__ Out)
{
    // A: 4 slots (par,half) of 128x64 i8 = 32 KiB; B same at +32768. 64 KiB total.
    __shared__ char sh[65536];

    const int tid  = threadIdx.x;
    const int lane = tid & 63;
    const int wid  = tid >> 6;
    const int wr   = wid >> 2;               // 0..1 : M 128-row half
    const int wc   = wid & 3;                // 0..3 : N 64-col quarter
    const int l15  = lane & 15;
    const int l4   = lane >> 4;

    // XCD-aware bijective swizzle, bm-major chunks per XCD
    const int wg  = ((int)blockIdx.x % 8) * CPX + (int)blockIdx.x / 8;
    const int bm = wg / NBN, bn = wg % NBN;
    const int m0 = bm * 256, n0 = bn * 256;

    // staging: thread covers row sr (0..127), 16B chunk (tid&3); linear LDS, no swizzle
    const int sr   = tid >> 2;
    const int sc16 = (tid & 3) * 16;
    const int ldo  = tid * 16;               // byte offset within 8KB slot
    const char* aSrc = Ab + (size_t)(m0 + sr) * Kdim + sc16;
    const char* bSrc = Bt + (size_t)(n0 + sr) * Kdim + sc16;

    auto stageA = [&](int tt, int h, int slot) {
        gload16(aSrc + (size_t)(h * 128) * Kdim + tt * 64, &sh[slot * 8192 + ldo]);
    };
    auto stageB = [&](int tt, int h, int slot) {
        gload16(bSrc + (size_t)(h * 128) * Kdim + tt * 64, &sh[32768 + slot * 8192 + ldo]);
    };

    i32x4 acc[8][4];
#pragma unroll
    for (int i = 0; i < 8; ++i)
#pragma unroll
        for (int j = 0; j < 4; ++j) acc[i][j] = (i32x4){0, 0, 0, 0};

    // prologue: tile0 A+B, tile1 B; wait tile0 (leave B(1)'s 2 in flight); barrier
    stageA(0, 0, 0); stageA(0, 1, 1);
    stageB(0, 0, 0); stageB(0, 1, 1);
    stageB(1, 0, 2); stageB(1, 1, 3);
    asm volatile("s_waitcnt vmcnt(2)" ::: "memory");
    __builtin_amdgcn_s_barrier();

    const int browb = (wc & 1) * 64;

    for (int t = 0; t < NT; ++t) {
        const int par = t & 1, parn = par ^ 1;
        const char* aslot = &sh[(par * 2 + wr) * 8192];
        const char* bslot = &sh[32768 + (par * 2 + (wc >> 1)) * 8192];

        // ---- reads: B (4) then A (8); each b128 covers full K=64 ----
        i32x4 bv[4], av[8];
#pragma unroll
        for (int fn = 0; fn < 4; ++fn)
            bv[fn] = *(const i32x4*)&bslot[(browb + fn * 16 + l15) * 64 + l4 * 16];
#pragma unroll
        for (int fm = 0; fm < 8; ++fm)
            av[fm] = *(const i32x4*)&aslot[(fm * 16 + l15) * 64 + l4 * 16];

        // stage A(t+1) -> parn slots (their readers finished before last end-barrier)
        if (t + 1 < NT) { stageA(t + 1, 0, parn * 2 + 0); stageA(t + 1, 1, parn * 2 + 1); }

        // ---- MFMA first half (rows 0-63) ----
        __builtin_amdgcn_s_setprio(1);
#pragma unroll
        for (int fm = 0; fm < 4; ++fm)
#pragma unroll
            for (int fn = 0; fn < 4; ++fn)
                acc[fm][fn] = __builtin_amdgcn_mfma_i32_16x16x64_i8(
                    av[fm], bv[fn], acc[fm][fn], 0, 0, 0);
        __builtin_amdgcn_s_setprio(0);

        // mid-barrier: every wave consumed its B reads (lgkm wait preceded its MFMAs)
        asm volatile("" ::: "memory");
        __builtin_amdgcn_s_barrier();

        // stage B(t+2) -> par slots (safe now)
        if (t + 2 < NT) { stageB(t + 2, 0, par * 2 + 0); stageB(t + 2, 1, par * 2 + 1); }

        // ---- MFMA second half (rows 64-127) ----
        __builtin_amdgcn_s_setprio(1);
#pragma unroll
        for (int fm = 4; fm < 8; ++fm)
#pragma unroll
            for (int fn = 0; fn < 4; ++fn)
                acc[fm][fn] = __builtin_amdgcn_mfma_i32_16x16x64_i8(
                    av[fm], bv[fn], acc[fm][fn], 0, 0, 0);
        __builtin_amdgcn_s_setprio(0);

        // counted wait: oldest 4 of 6 outstanding = B(t+1)+A(t+1); leave B(t+2)
        if (t < NT - 2)       asm volatile("s_waitcnt vmcnt(2)" ::: "memory");
        else if (t == NT - 2) asm volatile("s_waitcnt vmcnt(0)" ::: "memory");
        asm volatile("" ::: "memory");
        __builtin_amdgcn_s_barrier();
    }

    // ---- epilogue: out = sA[m]*sCol[n]*acc + bias; C/D col=lane&15, row=(lane>>4)*4+r ----
    const int rb = l4 * 4;
    float sc[4], bb[4];
#pragma unroll
    for (int fn = 0; fn < 4; ++fn) {
        const int ng = n0 + wc * 64 + fn * 16 + l15;
        sc[fn] = sCol[ng];
        bb[fn] = Bias[ng];
    }
#pragma unroll
    for (int fm = 0; fm < 8; ++fm) {
        const size_t mg = (size_t)(m0 + wr * 128 + fm * 16 + rb);
#pragma unroll
        for (int r = 0; r < 4; ++r) {
            const float sa = sA[mg + r];
#pragma unroll
            for (int fn = 0; fn < 4; ++fn) {
                const int ng = n0 + wc * 64 + fn * 16 + l15;
                Out[(mg + r) * Ndim + ng] = (float)acc[fm][fn][r] * sa * sc[fn] + bb[fn];
            }
        }
    }
}

// ---------------- fallback: fused bf16 kernel (if ws too small) ----------------
constexpr int SA = 72;
__global__ __launch_bounds__(256) void w4a32_fused_kernel(
    const float* __restrict__ A,
    const int* __restrict__ Wq,
    const float* __restrict__ Ws,
    const float* __restrict__ Bias,
    float* __restrict__ Out)
{
    __shared__ unsigned short As[128 * SA];
    __shared__ unsigned short Bs[128 * SA];
    const int tid = threadIdx.x;
    const int nbn = Ndim / 128;
    const int bn = blockIdx.x % nbn;
    const int bm = blockIdx.x / nbn;
    const int m0 = bm * 128, n0 = bn * 128;
    const int lane = tid & 63;
    const int wid  = tid >> 6;
    const int wr   = wid >> 1;
    const int wc   = wid & 1;
    const int l15  = lane & 15;
    const int l4   = lane >> 4;
    f32x4 acc[4][4];
#pragma unroll
    for (int i = 0; i < 4; ++i)
#pragma unroll
        for (int j = 0; j < 4; ++j) acc[i][j] = (f32x4){0.f, 0.f, 0.f, 0.f};
    const int a_tr = tid >> 3;
    const int a_tc = (tid & 7) * 8;
    const int kp2  = tid >> 4;
    const int n8   = (tid & 15) * 8;
    for (int kt = 0; kt < Kdim / 64; ++kt) {
        const int k0 = kt * 64;
        __syncthreads();
#pragma unroll
        for (int j = 0; j < 4; ++j) {
            const int ml = a_tr + 32 * j;
            const float* src = A + (size_t)(m0 + ml) * Kdim + (k0 + a_tc);
            const f32x4 x0 = *(const f32x4*)src;
            const f32x4 x1 = *(const f32x4*)(src + 4);
            union { bf16x8 v; unsigned short u[8]; } h;
            h.u[0] = f2bf(x0[0]); h.u[1] = f2bf(x0[1]);
            h.u[2] = f2bf(x0[2]); h.u[3] = f2bf(x0[3]);
            h.u[4] = f2bf(x1[0]); h.u[5] = f2bf(x1[1]);
            h.u[6] = f2bf(x1[2]); h.u[7] = f2bf(x1[3]);
            *(bf16x8*)(&As[ml * SA + (a_tc ^ ((ml & 7) << 3))]) = h.v;
        }
        {
            const int pr = kt * 32 + 2 * kp2;
            const int* wp = Wq + (size_t)pr * Ndim + (n0 + n8);
            const i32x4 r0a = *(const i32x4*)wp;
            const i32x4 r0b = *(const i32x4*)(wp + 4);
            const i32x4 r1a = *(const i32x4*)(wp + Ndim);
            const i32x4 r1b = *(const i32x4*)(wp + Ndim + 4);
            const int g = 2 * kt + (kp2 >> 3);
            const float* sp = Ws + (size_t)g * Ndim + (n0 + n8);
            const f32x4 s0 = *(const f32x4*)sp;
            const f32x4 s1 = *(const f32x4*)(sp + 4);
#pragma unroll
            for (int i = 0; i < 8; ++i) {
                const float s = (i < 4) ? s0[i] : s1[i - 4];
                const int b0 = (i < 4) ? r0a[i] : r0b[i - 4];
                const int b1 = (i < 4) ? r1a[i] : r1b[i - 4];
                union { unsigned long long v; unsigned short u[4]; } o;
                o.u[0] = f2bf((float)((b0 & 15) - 8) * s);
                o.u[1] = f2bf((float)(((b0 >> 4) & 15) - 8) * s);
                o.u[2] = f2bf((float)((b1 & 15) - 8) * s);
                o.u[3] = f2bf((float)(((b1 >> 4) & 15) - 8) * s);
                const int nl = n8 + i;
                const int swzz = ((nl ^ (nl >> 3)) & 7) << 3;
                *(unsigned long long*)(&Bs[nl * SA + ((4 * kp2) ^ swzz)]) = o.v;
            }
        }
        __syncthreads();
#pragma unroll
        for (int ks = 0; ks < 2; ++ks) {
            const int kb  = ks * 32 + l4 * 8;
            const int swa = (l15 & 7) << 3;
            bf16x8 af[4], bfr[4];
#pragma unroll
            for (int fm = 0; fm < 4; ++fm) {
                const int row = wr * 64 + fm * 16 + l15;
                af[fm] = *(const bf16x8*)(&As[row * SA + (kb ^ swa)]);
            }
#pragma unroll
            for (int fn = 0; fn < 4; ++fn) {
                const int nrow = wc * 64 + fn * 16 + l15;
                const int swb = ((nrow ^ (nrow >> 3)) & 7) << 3;
                bfr[fn] = *(const bf16x8*)(&Bs[nrow * SA + (kb ^ swb)]);
            }
#pragma unroll
            for (int fm = 0; fm < 4; ++fm)
#pragma unroll
                for (int fn = 0; fn < 4; ++fn)
                    acc[fm][fn] = __builtin_amdgcn_mfma_f32_16x16x32_bf16(
                        af[fm], bfr[fn], acc[fm][fn], 0, 0, 0);
        }
    }
    const int rb = l4 * 4;
    float bv[4];
#pragma unroll
    for (int fn = 0; fn < 4; ++fn)
        bv[fn] = Bias[n0 + wc * 64 + fn * 16 + l15];
#pragma unroll
    for (int fm = 0; fm < 4; ++fm) {
        const size_t mg = (size_t)(m0 + wr * 64 + fm * 16 + rb);
#pragma unroll
        for (int fn = 0; fn < 4; ++fn) {
            const int ng = n0 + wc * 64 + fn * 16 + l15;
            const float b = bv[fn];
#pragma unroll
            for (int r = 0; r < 4; ++r)
                Out[(mg + r) * Ndim + ng] = acc[fm][fn][r] + b;
        }
    }
}

extern "C" void kernel_launch(void* const* d_in, const int* in_sizes, int n_in,
                              void* d_out, int out_size, void* d_ws, size_t ws_size,
                              hipStream_t stream) {
    const float* A    = (const float*)d_in[0];
    const int* Wq     = (const int*)d_in[1];
    const float* Ws   = (const float*)d_in[2];
    const float* Bias = (const float*)d_in[3];
    float* Out        = (float*)d_out;

    const size_t offAq = 0;
    const size_t offWt = (size_t)Mdim * Kdim;                     // 33.5 MB
    const size_t offSA = offWt + (size_t)Ndim * Kdim;             // +45.1 MB
    const size_t offF  = offSA + (size_t)Mdim * 4;
    const size_t offSC = offF + (size_t)Ndim * 4;
    const size_t need  = offSC + (size_t)Ndim * 4;

    if (ws_size >= need) {
        char*  Aq   = (char*)d_ws + offAq;
        char*  Wt   = (char*)d_ws + offWt;
        float* sAp  = (float*)((char*)d_ws + offSA);
        float* Fc   = (float*)((char*)d_ws + offF);
        float* sCol = (float*)((char*)d_ws + offSC);
        quantA_kernel<<<Mdim, 256, 0, stream>>>(A, Aq, sAp);
        wscale_kernel<<<Ndim / 256, 256, 0, stream>>>(Ws, Fc, sCol);
        wq_kernel<<<(Kdim / 64) * (Ndim / 64), 256, 0, stream>>>(Wq, Ws, Fc, Wt);
        gemm_i8_kernel<<<NWG, 512, 0, stream>>>(Aq, Wt, sAp, sCol, Bias, Out);
    } else {
        w4a32_fused_kernel<<<(Mdim / 128) * (Ndim / 128), 256, 0, stream>>>(A, Wq, Ws, Bias, Out);
    }
}

// Round 14
// 490.898 us; speedup vs baseline: 2.2673x; 1.0761x over previous
//
#include <hip/hip_runtime.h>
#include <hip/hip_bf16.h>
#include <stdint.h>

typedef __attribute__((ext_vector_type(8))) short bf16x8;
typedef __attribute__((ext_vector_type(4))) float f32x4;
typedef __attribute__((ext_vector_type(4))) int i32x4;

constexpr int Mdim = 8192;
constexpr int Ndim = 11008;
constexpr int Kdim = 4096;
constexpr int NT = Kdim / 64;                       // 64 K-tiles of BK=64
constexpr int NWG = (Mdim / 256) * (Ndim / 256);    // 1376
constexpr int CPX = NWG / 8;                        // 172
constexpr int NBN = Ndim / 256;                     // 43

__device__ __forceinline__ unsigned short f2bf(float f) {
    __bf16 h = (__bf16)f;
    return __builtin_bit_cast(unsigned short, h);
}

__device__ __forceinline__ void gload16(const void* g, void* lds) {
    __builtin_amdgcn_global_load_lds(
        (const __attribute__((address_space(1))) unsigned int*)g,
        (__attribute__((address_space(3))) unsigned int*)lds,
        16, 0, 0);
}

// ---------------- prepass 1 (fused): A fp32->i8 per-row  ||  per-col fold factors ----------------
__global__ __launch_bounds__(256) void prepAS_kernel(const float* __restrict__ A,
                                                     char* __restrict__ Aq,
                                                     float* __restrict__ sA,
                                                     const float* __restrict__ Ws,
                                                     float* __restrict__ Fc,
                                                     float* __restrict__ sCol)
{
    const int tid = threadIdx.x;
    if (blockIdx.x >= Mdim) {
        // ---- per-column max over 128 group scales (coalesced across lanes) ----
        const int n = (blockIdx.x - Mdim) * 256 + tid;     // 43*256 = 11008 exact
        float mx = 0.f;
        for (int g = 0; g < 128; ++g) mx = fmaxf(mx, Ws[(size_t)g * Ndim + n]);
        Fc[n]   = 15.875f / mx;                            // 127/(8*mx)
        sCol[n] = mx * (8.0f / 127.0f);
        return;
    }
    // ---- A row quantize ----
    __shared__ float red[4];
    const int row = blockIdx.x;
    const float* src = A + (size_t)row * Kdim + tid * 16;
    f32x4 v[4];
    float m = 0.f;
#pragma unroll
    for (int j = 0; j < 4; ++j) {
        v[j] = *(const f32x4*)(src + j * 4);
#pragma unroll
        for (int e = 0; e < 4; ++e) m = fmaxf(m, fabsf(v[j][e]));
    }
#pragma unroll
    for (int o = 32; o > 0; o >>= 1) m = fmaxf(m, __shfl_down(m, o));
    if ((tid & 63) == 0) red[tid >> 6] = m;
    __syncthreads();
    m = fmaxf(fmaxf(red[0], red[1]), fmaxf(red[2], red[3]));
    const float inv = 127.0f / m;
    if (tid == 0) sA[row] = m * (1.0f / 127.0f);
    char out[16];
#pragma unroll
    for (int j = 0; j < 4; ++j)
#pragma unroll
        for (int e = 0; e < 4; ++e)
            out[j * 4 + e] = (char)__float2int_rn(v[j][e] * inv);
    *(i32x4*)(Aq + (size_t)row * Kdim + tid * 16) = *(const i32x4*)out;
}

// ---------------- prepass 2: W int4 -> i8 (scale-folded), transposed [N][K] ----------------
__global__ __launch_bounds__(256) void wq_kernel(const int* __restrict__ Wq,
                                                 const float* __restrict__ Ws,
                                                 const float* __restrict__ Fc,
                                                 char* __restrict__ Wt)
{
    __shared__ char T[64][80];
    const int kt = blockIdx.x % (Kdim / 64);
    const int nt = blockIdx.x / (Kdim / 64);
    const int k0 = kt * 64, n0 = nt * 64;
    const int t = threadIdx.x;

    const int pr   = t >> 3;                 // 0..31 packed row
    const int nloc = (t & 7) * 8;
    const int* wp = Wq + (size_t)(k0 / 2 + pr) * Ndim + n0 + nloc;
    const i32x4 ra = *(const i32x4*)wp;
    const i32x4 rb = *(const i32x4*)(wp + 4);
    const int g = (k0 + 2 * pr) >> 5;
    const float* sp = Ws + (size_t)g * Ndim + n0 + nloc;
    const f32x4 s0 = *(const f32x4*)sp;
    const f32x4 s1 = *(const f32x4*)(sp + 4);
    const f32x4 f0 = *(const f32x4*)(Fc + n0 + nloc);
    const f32x4 f1 = *(const f32x4*)(Fc + n0 + nloc + 4);
#pragma unroll
    for (int i = 0; i < 8; ++i) {
        const int v = (i < 4) ? ra[i] : rb[i - 4];
        const float sf = ((i < 4) ? s0[i] : s1[i - 4]) * ((i < 4) ? f0[i] : f1[i - 4]);
        T[nloc + i][2 * pr]     = (char)__float2int_rn((float)((v & 15) - 8) * sf);
        T[nloc + i][2 * pr + 1] = (char)__float2int_rn((float)(((v >> 4) & 15) - 8) * sf);
    }
    __syncthreads();
    const int nl = t >> 2;
    const int ko = (t & 3) * 16;
    const i32x4 o = *(const i32x4*)&T[nl][ko];
    *(i32x4*)(Wt + (size_t)(n0 + nl) * Kdim + k0 + ko) = o;
}

// ---- main GEMM: 256x256x64, 8 waves, i8 MFMA K=64, quarter-wave bank swizzle ----
__global__ __launch_bounds__(512, 2) void gemm_i8_kernel(
    const char* __restrict__ Ab,
    const char* __restrict__ Bt,
    const float* __restrict__ sA,
    const float* __restrict__ sCol,
    const float* __restrict__ Bias,
    float* __restrict__ Out)
{
    // A: 4 slots (par,half) of 128x64 i8 = 32 KiB; B same at +32768. 64 KiB total.
    __shared__ char sh[65536];

    const int tid  = threadIdx.x;
    const int lane = tid & 63;
    const int wid  = tid >> 6;
    const int wr   = wid >> 2;               // 0..1 : M 128-row half
    const int wc   = wid & 3;                // 0..3 : N 64-col quarter
    const int l15  = lane & 15;
    const int l4   = lane >> 4;
    // quarter-wave-uniform slot swizzle: phys 16B-slot = l4 ^ ((row>>1)&3); row≡l15 (mod 8)
    const int rcol = ((l4 ^ ((l15 >> 1) & 3)) << 4);

    // XCD-aware bijective swizzle, bm-major chunks per XCD
    const int wg  = ((int)blockIdx.x % 8) * CPX + (int)blockIdx.x / 8;
    const int bm = wg / NBN, bn = wg % NBN;
    const int m0 = bm * 256, n0 = bn * 256;

    // staging: thread covers row sr (0..127), phys slot (tid&3); source chunk pre-swizzled
    const int sr   = tid >> 2;
    const int sc16 = ((tid & 3) ^ ((tid >> 3) & 3)) * 16;
    const int ldo  = tid * 16;               // linear LDS dest (DMA requirement)
    const char* aSrc = Ab + (size_t)(m0 + sr) * Kdim + sc16;
    const char* bSrc = Bt + (size_t)(n0 + sr) * Kdim + sc16;

    auto stageA = [&](int tt, int h, int slot) {
        gload16(aSrc + (size_t)(h * 128) * Kdim + tt * 64, &sh[slot * 8192 + ldo]);
    };
    auto stageB = [&](int tt, int h, int slot) {
        gload16(bSrc + (size_t)(h * 128) * Kdim + tt * 64, &sh[32768 + slot * 8192 + ldo]);
    };

    i32x4 acc[8][4];
#pragma unroll
    for (int i = 0; i < 8; ++i)
#pragma unroll
        for (int j = 0; j < 4; ++j) acc[i][j] = (i32x4){0, 0, 0, 0};

    // prologue: tile0 A+B, tile1 B; wait tile0 (leave B(1)'s 2 in flight); barrier
    stageA(0, 0, 0); stageA(0, 1, 1);
    stageB(0, 0, 0); stageB(0, 1, 1);
    stageB(1, 0, 2); stageB(1, 1, 3);
    asm volatile("s_waitcnt vmcnt(2)" ::: "memory");
    __builtin_amdgcn_s_barrier();

    const int browb = (wc & 1) * 64;

    for (int t = 0; t < NT; ++t) {
        const int par = t & 1, parn = par ^ 1;
        const char* aslot = &sh[(par * 2 + wr) * 8192];
        const char* bslot = &sh[32768 + (par * 2 + (wc >> 1)) * 8192];

        // ---- reads: B (4) then A (8); each b128 covers full K=64, swizzled slots ----
        i32x4 bv[4], av[8];
#pragma unroll
        for (int fn = 0; fn < 4; ++fn)
            bv[fn] = *(const i32x4*)&bslot[(browb + fn * 16 + l15) * 64 + rcol];
#pragma unroll
        for (int fm = 0; fm < 8; ++fm)
            av[fm] = *(const i32x4*)&aslot[(fm * 16 + l15) * 64 + rcol];

        // stage A(t+1) -> parn slots (their readers finished before last end-barrier)
        if (t + 1 < NT) { stageA(t + 1, 0, parn * 2 + 0); stageA(t + 1, 1, parn * 2 + 1); }

        // ---- MFMA first half (rows 0-63) ----
        __builtin_amdgcn_s_setprio(1);
#pragma unroll
        for (int fm = 0; fm < 4; ++fm)
#pragma unroll
            for (int fn = 0; fn < 4; ++fn)
                acc[fm][fn] = __builtin_amdgcn_mfma_i32_16x16x64_i8(
                    av[fm], bv[fn], acc[fm][fn], 0, 0, 0);
        __builtin_amdgcn_s_setprio(0);

        // mid-barrier: every wave consumed its B reads (lgkm wait preceded its MFMAs)
        asm volatile("" ::: "memory");
        __builtin_amdgcn_s_barrier();

        // stage B(t+2) -> par slots (safe now)
        if (t + 2 < NT) { stageB(t + 2, 0, par * 2 + 0); stageB(t + 2, 1, par * 2 + 1); }

        // ---- MFMA second half (rows 64-127) ----
        __builtin_amdgcn_s_setprio(1);
#pragma unroll
        for (int fm = 4; fm < 8; ++fm)
#pragma unroll
            for (int fn = 0; fn < 4; ++fn)
                acc[fm][fn] = __builtin_amdgcn_mfma_i32_16x16x64_i8(
                    av[fm], bv[fn], acc[fm][fn], 0, 0, 0);
        __builtin_amdgcn_s_setprio(0);

        // counted wait: oldest 4 of 6 outstanding = B(t+1)+A(t+1); leave B(t+2)
        if (t < NT - 2)       asm volatile("s_waitcnt vmcnt(2)" ::: "memory");
        else if (t == NT - 2) asm volatile("s_waitcnt vmcnt(0)" ::: "memory");
        asm volatile("" ::: "memory");
        __builtin_amdgcn_s_barrier();
    }

    // ---- epilogue: out = sA[m]*sCol[n]*acc + bias; C/D col=lane&15, row=(lane>>4)*4+r ----
    const int rb = l4 * 4;
    float sc[4], bb[4];
#pragma unroll
    for (int fn = 0; fn < 4; ++fn) {
        const int ng = n0 + wc * 64 + fn * 16 + l15;
        sc[fn] = sCol[ng];
        bb[fn] = Bias[ng];
    }
#pragma unroll
    for (int fm = 0; fm < 8; ++fm) {
        const size_t mg = (size_t)(m0 + wr * 128 + fm * 16 + rb);
#pragma unroll
        for (int r = 0; r < 4; ++r) {
            const float sa = sA[mg + r];
#pragma unroll
            for (int fn = 0; fn < 4; ++fn) {
                const int ng = n0 + wc * 64 + fn * 16 + l15;
                __builtin_nontemporal_store((float)acc[fm][fn][r] * sa * sc[fn] + bb[fn],
                                            &Out[(mg + r) * Ndim + ng]);
            }
        }
    }
}

// ---------------- fallback: fused bf16 kernel (if ws too small) ----------------
constexpr int SA = 72;
__global__ __launch_bounds__(256) void w4a32_fused_kernel(
    const float* __restrict__ A,
    const int* __restrict__ Wq,
    const float* __restrict__ Ws,
    const float* __restrict__ Bias,
    float* __restrict__ Out)
{
    __shared__ unsigned short As[128 * SA];
    __shared__ unsigned short Bs[128 * SA];
    const int tid = threadIdx.x;
    const int nbn = Ndim / 128;
    const int bn = blockIdx.x % nbn;
    const int bm = blockIdx.x / nbn;
    const int m0 = bm * 128, n0 = bn * 128;
    const int lane = tid & 63;
    const int wid  = tid >> 6;
    const int wr   = wid >> 1;
    const int wc   = wid & 1;
    const int l15  = lane & 15;
    const int l4   = lane >> 4;
    f32x4 acc[4][4];
#pragma unroll
    for (int i = 0; i < 4; ++i)
#pragma unroll
        for (int j = 0; j < 4; ++j) acc[i][j] = (f32x4){0.f, 0.f, 0.f, 0.f};
    const int a_tr = tid >> 3;
    const int a_tc = (tid & 7) * 8;
    const int kp2  = tid >> 4;
    const int n8   = (tid & 15) * 8;
    for (int kt = 0; kt < Kdim / 64; ++kt) {
        const int k0 = kt * 64;
        __syncthreads();
#pragma unroll
        for (int j = 0; j < 4; ++j) {
            const int ml = a_tr + 32 * j;
            const float* src = A + (size_t)(m0 + ml) * Kdim + (k0 + a_tc);
            const f32x4 x0 = *(const f32x4*)src;
            const f32x4 x1 = *(const f32x4*)(src + 4);
            union { bf16x8 v; unsigned short u[8]; } h;
            h.u[0] = f2bf(x0[0]); h.u[1] = f2bf(x0[1]);
            h.u[2] = f2bf(x0[2]); h.u[3] = f2bf(x0[3]);
            h.u[4] = f2bf(x1[0]); h.u[5] = f2bf(x1[1]);
            h.u[6] = f2bf(x1[2]); h.u[7] = f2bf(x1[3]);
            *(bf16x8*)(&As[ml * SA + (a_tc ^ ((ml & 7) << 3))]) = h.v;
        }
        {
            const int pr = kt * 32 + 2 * kp2;
            const int* wp = Wq + (size_t)pr * Ndim + (n0 + n8);
            const i32x4 r0a = *(const i32x4*)wp;
            const i32x4 r0b = *(const i32x4*)(wp + 4);
            const i32x4 r1a = *(const i32x4*)(wp + Ndim);
            const i32x4 r1b = *(const i32x4*)(wp + Ndim + 4);
            const int g = 2 * kt + (kp2 >> 3);
            const float* sp = Ws + (size_t)g * Ndim + (n0 + n8);
            const f32x4 s0 = *(const f32x4*)sp;
            const f32x4 s1 = *(const f32x4*)(sp + 4);
#pragma unroll
            for (int i = 0; i < 8; ++i) {
                const float s = (i < 4) ? s0[i] : s1[i - 4];
                const int b0 = (i < 4) ? r0a[i] : r0b[i - 4];
                const int b1 = (i < 4) ? r1a[i] : r1b[i - 4];
                union { unsigned long long v; unsigned short u[4]; } o;
                o.u[0] = f2bf((float)((b0 & 15) - 8) * s);
                o.u[1] = f2bf((float)(((b0 >> 4) & 15) - 8) * s);
                o.u[2] = f2bf((float)((b1 & 15) - 8) * s);
                o.u[3] = f2bf((float)(((b1 >> 4) & 15) - 8) * s);
                const int nl = n8 + i;
                const int swzz = ((nl ^ (nl >> 3)) & 7) << 3;
                *(unsigned long long*)(&Bs[nl * SA + ((4 * kp2) ^ swzz)]) = o.v;
            }
        }
        __syncthreads();
#pragma unroll
        for (int ks = 0; ks < 2; ++ks) {
            const int kb  = ks * 32 + l4 * 8;
            const int swa = (l15 & 7) << 3;
            bf16x8 af[4], bfr[4];
#pragma unroll
            for (int fm = 0; fm < 4; ++fm) {
                const int row = wr * 64 + fm * 16 + l15;
                af[fm] = *(const bf16x8*)(&As[row * SA + (kb ^ swa)]);
            }
#pragma unroll
            for (int fn = 0; fn < 4; ++fn) {
                const int nrow = wc * 64 + fn * 16 + l15;
                const int swb = ((nrow ^ (nrow >> 3)) & 7) << 3;
                bfr[fn] = *(const bf16x8*)(&Bs[nrow * SA + (kb ^ swb)]);
            }
#pragma unroll
            for (int fm = 0; fm < 4; ++fm)
#pragma unroll
                for (int fn = 0; fn < 4; ++fn)
                    acc[fm][fn] = __builtin_amdgcn_mfma_f32_16x16x32_bf16(
                        af[fm], bfr[fn], acc[fm][fn], 0, 0, 0);
        }
    }
    const int rb = l4 * 4;
    float bv[4];
#pragma unroll
    for (int fn = 0; fn < 4; ++fn)
        bv[fn] = Bias[n0 + wc * 64 + fn * 16 + l15];
#pragma unroll
    for (int fm = 0; fm < 4; ++fm) {
        const size_t mg = (size_t)(m0 + wr * 64 + fm * 16 + rb);
#pragma unroll
        for (int fn = 0; fn < 4; ++fn) {
            const int ng = n0 + wc * 64 + fn * 16 + l15;
            const float b = bv[fn];
#pragma unroll
            for (int r = 0; r < 4; ++r)
                Out[(mg + r) * Ndim + ng] = acc[fm][fn][r] + b;
        }
    }
}

extern "C" void kernel_launch(void* const* d_in, const int* in_sizes, int n_in,
                              void* d_out, int out_size, void* d_ws, size_t ws_size,
                              hipStream_t stream) {
    const float* A    = (const float*)d_in[0];
    const int* Wq     = (const int*)d_in[1];
    const float* Ws   = (const float*)d_in[2];
    const float* Bias = (const float*)d_in[3];
    float* Out        = (float*)d_out;

    const size_t offAq = 0;
    const size_t offWt = (size_t)Mdim * Kdim;                     // 33.5 MB
    const size_t offSA = offWt + (size_t)Ndim * Kdim;             // +45.1 MB
    const size_t offF  = offSA + (size_t)Mdim * 4;
    const size_t offSC = offF + (size_t)Ndim * 4;
    const size_t need  = offSC + (size_t)Ndim * 4;

    if (ws_size >= need) {
        char*  Aq   = (char*)d_ws + offAq;
        char*  Wt   = (char*)d_ws + offWt;
        float* sAp  = (float*)((char*)d_ws + offSA);
        float* Fc   = (float*)((char*)d_ws + offF);
        float* sCol = (float*)((char*)d_ws + offSC);
        prepAS_kernel<<<Mdim + Ndim / 256, 256, 0, stream>>>(A, Aq, sAp, Ws, Fc, sCol);
        wq_kernel<<<(Kdim / 64) * (Ndim / 64), 256, 0, stream>>>(Wq, Ws, Fc, Wt);
        gemm_i8_kernel<<<NWG, 512, 0, stream>>>(Aq, Wt, sAp, sCol, Bias, Out);
    } else {
        w4a32_fused_kernel<<<(Mdim / 128) * (Ndim / 128), 256, 0, stream>>>(A, Wq, Ws, Bias, Out);
    }
}